// Round 5
// baseline (403.562 us; speedup 1.0000x reference)
//
#include <hip/hip_runtime.h>
#include <cstdint>
#include <cstddef>

#define N_NODESC 50000
#define N_PAD    50048   // 391 * 128
#define N_EDGESC 600000
#define N_GRAPHSC 64
#define D_HIDC   128
#define D_LATC   64
#define D_GS     512     // G = [mean, max, min, std] (h section read from h directly)
#define D_WROW   1664    // transposed W row length (13*128)

typedef unsigned short u16;
typedef unsigned int   u32;

typedef _Float16 f16x8 __attribute__((ext_vector_type(8)));
typedef _Float16 f16x2 __attribute__((ext_vector_type(2)));
typedef float    f32x4 __attribute__((ext_vector_type(4)));
typedef float    f32x2 __attribute__((ext_vector_type(2)));

__device__ __forceinline__ u16 f2h(float f) {
    return __builtin_bit_cast(u16, (_Float16)f);
}
__device__ __forceinline__ float h2f(u16 u) {
    return (float)__builtin_bit_cast(_Float16, u);
}

// packed f32 ops (force v_pk_* codegen; pure-VALU asm, no ordering hazard)
__device__ __forceinline__ f32x2 pk_add(f32x2 a, f32x2 b) {
    f32x2 d;
    asm("v_pk_add_f32 %0, %1, %2" : "=v"(d) : "v"(a), "v"(b));
    return d;
}
__device__ __forceinline__ f32x2 pk_fma(f32x2 a, f32x2 b, f32x2 c) {
    f32x2 d;
    asm("v_pk_fma_f32 %0, %1, %2, %3" : "=v"(d) : "v"(a), "v"(b), "v"(c));
    return d;
}

__device__ __forceinline__ void gll16(void* lds, const void* g) {
    // async global->LDS, 16B per lane; HW dest = wave-uniform base + lane*16
    __builtin_amdgcn_global_load_lds(
        (const __attribute__((address_space(1))) void*)g,
        (__attribute__((address_space(3))) void*)lds, 16, 0, 0);
}

// ---------------- fused setup ----------------
// block ranges: [0,ZB) zero | [ZB,ZB+12500) x2h | next 2496 wconv | last goff
__global__ void __launch_bounds__(256) k_setup(
        const float* __restrict__ x, const float* __restrict__ W0,
        const float* __restrict__ W1, const float* __restrict__ W2,
        const int* __restrict__ batch,
        u16* __restrict__ h, u16* __restrict__ Wt,
        int* __restrict__ zero_base, int nz, int ZB, int* __restrict__ goff) {
    int b = blockIdx.x;
    int t = threadIdx.x;
    if (b < ZB) {
        int i = b * 256 + t;
        if (i < nz) zero_base[i] = 0;
        return;
    }
    b -= ZB;
    if (b < 12500) {                       // x -> fp16 (2 elems/thread)
        int i = b * 256 + t;
        float2 v = ((const float2*)x)[i];
        ((u32*)h)[i] = (u32)f2h(v.x) | ((u32)f2h(v.y) << 16);
        return;
    }
    b -= 12500;
    if (b < 2496) {                        // W transpose+cast: [1664][128] -> [128][1664]
        int which = b / 832;
        int i = (b % 832) * 256 + t;
        const float* W = (which == 0) ? W0 : (which == 1) ? W1 : W2;
        int k = i / D_HIDC, j = i % D_HIDC;
        Wt[(size_t)which * D_WROW * D_HIDC + (size_t)j * D_WROW + k] = f2h(W[i]);
        return;
    }
    // goff via binary search over sorted batch
    int g = t;
    if (g <= N_GRAPHSC) {
        int lo = 0, hi = N_NODESC;
        while (lo < hi) {
            int mid = (lo + hi) >> 1;
            if (batch[mid] < g) lo = mid + 1; else hi = mid;
        }
        goff[g] = lo;
    }
}

__global__ void k_count(const int* __restrict__ dst, int* __restrict__ deg) {
    int e = blockIdx.x * 256 + threadIdx.x;
    if (e < N_EDGESC) atomicAdd(&deg[dst[e]], 1);
}

// 196 blocks: per-block int sum -> bsum, per-block logf sum -> lsum
__global__ void __launch_bounds__(256) k_scan_part(
        const int* __restrict__ deg, int* __restrict__ bsum,
        float* __restrict__ lsum) {
    __shared__ int s[256];
    __shared__ float ls[256];
    int idx = blockIdx.x * 256 + threadIdx.x;
    int v = (idx < N_NODESC) ? deg[idx] : 0;
    s[threadIdx.x] = v;
    ls[threadIdx.x] = (idx < N_NODESC) ? logf((float)v + 1.0f) : 0.0f;
    __syncthreads();
    for (int o = 128; o > 0; o >>= 1) {
        if (threadIdx.x < o) {
            s[threadIdx.x] += s[threadIdx.x + o];
            ls[threadIdx.x] += ls[threadIdx.x + o];
        }
        __syncthreads();
    }
    if (threadIdx.x == 0) { bsum[blockIdx.x] = s[0]; lsum[blockIdx.x] = ls[0]; }
}

// 1 block: exclusive-scan bsum (196 entries) + reduce lsum -> delta
__global__ void __launch_bounds__(256) k_scan_block(
        int* __restrict__ bsum, const float* __restrict__ lsum,
        float* __restrict__ delta_p) {
    __shared__ int s[256];
    __shared__ float ls[256];
    int t = threadIdx.x;
    int v = (t < 196) ? bsum[t] : 0;
    s[t] = v;
    ls[t] = (t < 196) ? lsum[t] : 0.0f;
    __syncthreads();
    for (int o = 1; o < 256; o <<= 1) {
        int add = (t >= o) ? s[t - o] : 0;
        __syncthreads();
        s[t] += add;
        __syncthreads();
    }
    if (t < 196) bsum[t] = s[t] - v;   // exclusive
    for (int o = 128; o > 0; o >>= 1) {
        if (t < o) ls[t] += ls[t + o];
        __syncthreads();
    }
    if (t == 0) delta_p[0] = ls[0] * (1.0f / (float)N_NODESC);
}

// 196 blocks: block-local exclusive scan + block offset -> row_off
__global__ void __launch_bounds__(256) k_scan_final(
        const int* __restrict__ deg, const int* __restrict__ bsum,
        int* __restrict__ row_off) {
    __shared__ int s[256];
    int t = threadIdx.x;
    int idx = blockIdx.x * 256 + t;
    int v = (idx < N_NODESC) ? deg[idx] : 0;
    s[t] = v; __syncthreads();
    for (int o = 1; o < 256; o <<= 1) {
        int add = (t >= o) ? s[t - o] : 0;
        __syncthreads();
        s[t] += add;
        __syncthreads();
    }
    int excl = s[t] - v + bsum[blockIdx.x];
    if (idx < N_NODESC) row_off[idx] = excl;
    if (idx == 0) row_off[N_NODESC] = N_EDGESC;
}

// csr stores PRE-SCALED byte offsets (src*256) so gathers are base+u32 voffset
__global__ void k_fill_csr(const int* __restrict__ src, const int* __restrict__ dst,
                           const int* __restrict__ row_off, int* __restrict__ cursor,
                           int* __restrict__ csr_src) {
    int e = blockIdx.x * 256 + threadIdx.x;
    if (e < N_EDGESC) {
        int d = dst[e];
        int pos = row_off[d] + atomicAdd(&cursor[d], 1);
        csr_src[pos] = src[e] << 8;   // byte offset into h (128 * 2B per row)
    }
}

// ---------------- per-layer kernels ----------------

// one wave per node; two half-waves over alternate edges; 4 loads in flight
// per half-wave; packed f32 sum/sq (v_pk_*), exact fp16 packed min/max.
// G[n] = [mean, max, min, std] fp16 (h section read by gemm directly).
__global__ void __launch_bounds__(256) k_aggregate(
        const u16* __restrict__ h, const int* __restrict__ row_off,
        const int* __restrict__ csr_src, u16* __restrict__ G) {
    int n = blockIdx.x * 4 + (threadIdx.x >> 6);
    if (n >= N_NODESC) return;
    int lane = threadIdx.x & 63;
    int half = lane >> 5, l32 = lane & 31;
    int c4 = 4 * l32;
    u32 c8 = 8u * (u32)l32;
    const char* h8 = (const char*)h;
    int beg = row_off[n], end = row_off[n + 1];
    const _Float16 NEG = (_Float16)(-65504.0f), POS = (_Float16)(65504.0f);
    f32x2 s01 = {0.f, 0.f}, s23 = {0.f, 0.f};
    f32x2 q01 = {0.f, 0.f}, q23 = {0.f, 0.f};
    f16x2 mx01 = {NEG, NEG}, mx23 = {NEG, NEG};
    f16x2 mn01 = {POS, POS}, mn23 = {POS, POS};

    #define PROC(u) { \
        f16x2 p01 = __builtin_bit_cast(f16x2, (u).x); \
        f16x2 p23 = __builtin_bit_cast(f16x2, (u).y); \
        f32x2 c01 = __builtin_convertvector(p01, f32x2); \
        f32x2 c23 = __builtin_convertvector(p23, f32x2); \
        s01 = pk_add(s01, c01); s23 = pk_add(s23, c23); \
        q01 = pk_fma(c01, c01, q01); q23 = pk_fma(c23, c23, q23); \
        mx01 = __builtin_elementwise_max(mx01, p01); \
        mx23 = __builtin_elementwise_max(mx23, p23); \
        mn01 = __builtin_elementwise_min(mn01, p01); \
        mn23 = __builtin_elementwise_min(mn23, p23); }

    int i = beg + half;
    for (; i + 6 < end; i += 8) {
        u32 e0 = (u32)csr_src[i],     e1 = (u32)csr_src[i + 2];
        u32 e2 = (u32)csr_src[i + 4], e3 = (u32)csr_src[i + 6];
        uint2 u0 = *(const uint2*)(h8 + (e0 + c8));
        uint2 u1 = *(const uint2*)(h8 + (e1 + c8));
        uint2 u2 = *(const uint2*)(h8 + (e2 + c8));
        uint2 u3 = *(const uint2*)(h8 + (e3 + c8));
        PROC(u0); PROC(u1); PROC(u2); PROC(u3);
    }
    for (; i < end; i += 2) {
        u32 e0 = (u32)csr_src[i];
        uint2 u0 = *(const uint2*)(h8 + (e0 + c8));
        PROC(u0);
    }
    #undef PROC

    // merge half-waves (lane^32 holds same columns, other edges)
    s01.x += __shfl_xor(s01.x, 32); s01.y += __shfl_xor(s01.y, 32);
    s23.x += __shfl_xor(s23.x, 32); s23.y += __shfl_xor(s23.y, 32);
    q01.x += __shfl_xor(q01.x, 32); q01.y += __shfl_xor(q01.y, 32);
    q23.x += __shfl_xor(q23.x, 32); q23.y += __shfl_xor(q23.y, 32);
    #define MRG(v, OP) v = OP(v, \
        __builtin_bit_cast(f16x2, __shfl_xor(__builtin_bit_cast(int, v), 32)))
    MRG(mx01, __builtin_elementwise_max); MRG(mx23, __builtin_elementwise_max);
    MRG(mn01, __builtin_elementwise_min); MRG(mn23, __builtin_elementwise_min);
    #undef MRG

    int d = end - beg;
    float inv = 1.0f / fmaxf((float)d, 1.0f);
    float me0 = s01.x * inv, me1 = s01.y * inv;
    float me2 = s23.x * inv, me3 = s23.y * inv;
    float sd0 = sqrtf(fmaxf(q01.x * inv - me0 * me0, 0.0f) + 1e-5f);
    float sd1 = sqrtf(fmaxf(q01.y * inv - me1 * me1, 0.0f) + 1e-5f);
    float sd2 = sqrtf(fmaxf(q23.x * inv - me2 * me2, 0.0f) + 1e-5f);
    float sd3 = sqrtf(fmaxf(q23.y * inv - me3 * me3, 0.0f) + 1e-5f);
    float fx0 = (float)mx01.x, fx1 = (float)mx01.y;
    float fx2 = (float)mx23.x, fx3 = (float)mx23.y;
    float fn0 = (float)mn01.x, fn1 = (float)mn01.y;
    float fn2 = (float)mn23.x, fn3 = (float)mn23.y;
    if (d == 0) {
        fx0 = fx1 = fx2 = fx3 = 0.0f;
        fn0 = fn1 = fn2 = fn3 = 0.0f;
    }
    u16* base = G + (size_t)n * D_GS;
    #define PK2(a, b) ((u32)f2h(a) | ((u32)f2h(b) << 16))
    if (half == 0) {
        uint2 m; m.x = PK2(me0, me1); m.y = PK2(me2, me3);
        *(uint2*)(base + c4) = m;
        uint2 X; X.x = PK2(fx0, fx1); X.y = PK2(fx2, fx3);
        *(uint2*)(base + 128 + c4) = X;
    } else {
        uint2 N_; N_.x = PK2(fn0, fn1); N_.y = PK2(fn2, fn3);
        *(uint2*)(base + 256 + c4) = N_;
        uint2 S; S.x = PK2(sd0, sd1); S.y = PK2(sd2, sd3);
        *(uint2*)(base + 384 + c4) = S;
    }
    #undef PK2
}

// h_out[n][j] = relu(bias + B*W1 + am*(S*W2) + at*(S*W3)) over logical B = [h|G]
// R5: counted-vmcnt double-buffered K-pipeline (T3/T4), BK=32, 20 iters.
// LDS = 2 x (A1+A2+A3+Bt @ 8 KB) = 64 KB -> 2 blocks/CU. Per iter: issue next
// tile's global_load_lds, s_waitcnt vmcnt(L_next) (current tile's loads are the
// oldest -> they drain; next tile's stay IN FLIGHT across the barrier), raw
// s_barrier, ds_read+MFMA (setprio-wrapped), s_barrier. Never vmcnt(0) in loop.
// XOR-4 chunk swizzle (stage-source and read use same involution chunk^=row&3).
__global__ void __launch_bounds__(256, 2) k_gemm(
        const u16* __restrict__ hin, const u16* __restrict__ G,
        const u16* __restrict__ Wt,
        const int* __restrict__ deg, const float* __restrict__ delta_p,
        const float* __restrict__ bias, u16* __restrict__ hout) {
    __shared__ _Float16 A1[2][128 * 32];   // 8 KB x2 (W1 K-slab)
    __shared__ _Float16 A2[2][128 * 32];   // 8 KB x2 (W2)
    __shared__ _Float16 A3[2][128 * 32];   // 8 KB x2 (W3)
    __shared__ _Float16 Bt[2][128 * 32];   // 8 KB x2 (B tile)
    const _Float16* Wf = (const _Float16*)Wt;
    const _Float16* Gf = (const _Float16*)G;
    const _Float16* Hf = (const _Float16*)hin;
    int n0 = blockIdx.x * 128;
    int t = threadIdx.x;
    int w = t >> 6, lane = t & 63;
    int srow4 = lane >> 2, schk = lane & 3;
    int scol = (schk ^ (srow4 & 3)) * 8;   // inverse-swizzled source chunk (elems)
    int q4 = lane >> 4, r16 = lane & 15;
    int sx = (q4 ^ (r16 & 3)) * 8;         // swizzled read chunk (elems)
    int col = r16;
    int iA0 = w, iA1 = 4 + w;              // 16-row stage-inst indices per wave

    const _Float16* wA0 = Wf + (size_t)(iA0 * 16 + srow4) * D_WROW + scol;
    const _Float16* wA1 = Wf + (size_t)(iA1 * 16 + srow4) * D_WROW + scol;
    const _Float16* hB0 = Hf + (size_t)(n0 + iA0 * 16 + srow4) * D_HIDC + scol;
    const _Float16* hB1 = Hf + (size_t)(n0 + iA1 * 16 + srow4) * D_HIDC + scol;
    const _Float16* gB0 = Gf + (size_t)(n0 + iA0 * 16 + srow4) * D_GS + scol - 128;
    const _Float16* gB1 = Gf + (size_t)(n0 + iA1 * 16 + srow4) * D_GS + scol - 128;

    float delta = delta_p[0];
    float atv[8];
    _Float16 amh[8];
    #pragma unroll
    for (int nt = 0; nt < 8; nt++) {
        int node = n0 + nt * 16 + col;
        float logd = logf((float)deg[node] + 1.0f);
        amh[nt] = (_Float16)(logd / delta);
        atv[nt] = delta / fmaxf(logd, 1e-5f);
    }

    f32x4 acc[2][8], ac3[2][8];
    #pragma unroll
    for (int a = 0; a < 2; a++)
        #pragma unroll
        for (int b = 0; b < 8; b++) {
            acc[a][b] = (f32x4){0.f, 0.f, 0.f, 0.f};
            ac3[a][b] = (f32x4){0.f, 0.f, 0.f, 0.f};
        }

    #define STAGE(KI, BUF) do { \
        gll16(&A1[BUF][iA0 * 512], wA0 + (KI) * 32); \
        gll16(&A1[BUF][iA1 * 512], wA1 + (KI) * 32); \
        if ((KI) >= 4) { \
            gll16(&A2[BUF][iA0 * 512], wA0 + 512 + (KI) * 32); \
            gll16(&A2[BUF][iA1 * 512], wA1 + 512 + (KI) * 32); \
            gll16(&A3[BUF][iA0 * 512], wA0 + 1024 + (KI) * 32); \
            gll16(&A3[BUF][iA1 * 512], wA1 + 1024 + (KI) * 32); \
            gll16(&Bt[BUF][iA0 * 512], gB0 + (KI) * 32); \
            gll16(&Bt[BUF][iA1 * 512], gB1 + (KI) * 32); \
        } else { \
            gll16(&Bt[BUF][iA0 * 512], hB0 + (KI) * 32); \
            gll16(&Bt[BUF][iA1 * 512], hB1 + (KI) * 32); \
        } \
    } while (0)

    #define COMPUTE(KI, BUF) do { \
        f16x8 a00 = *(const f16x8*)&A1[BUF][(w * 32 + r16) * 32 + sx]; \
        f16x8 a10 = *(const f16x8*)&A1[BUF][(w * 32 + 16 + r16) * 32 + sx]; \
        if ((KI) < 4) { \
            _Pragma("unroll") \
            for (int nt = 0; nt < 8; nt++) { \
                f16x8 b0 = *(const f16x8*)&Bt[BUF][(nt * 16 + r16) * 32 + sx]; \
                acc[0][nt] = __builtin_amdgcn_mfma_f32_16x16x32_f16(a00, b0, acc[0][nt], 0, 0, 0); \
                acc[1][nt] = __builtin_amdgcn_mfma_f32_16x16x32_f16(a10, b0, acc[1][nt], 0, 0, 0); \
            } \
        } else { \
            f16x8 w2l = *(const f16x8*)&A2[BUF][(w * 32 + r16) * 32 + sx]; \
            f16x8 w2h = *(const f16x8*)&A2[BUF][(w * 32 + 16 + r16) * 32 + sx]; \
            f16x8 w3l = *(const f16x8*)&A3[BUF][(w * 32 + r16) * 32 + sx]; \
            f16x8 w3h = *(const f16x8*)&A3[BUF][(w * 32 + 16 + r16) * 32 + sx]; \
            _Pragma("unroll") \
            for (int nt = 0; nt < 8; nt++) { \
                f16x8 b0 = *(const f16x8*)&Bt[BUF][(nt * 16 + r16) * 32 + sx]; \
                f16x8 bm = b0 * amh[nt]; \
                acc[0][nt] = __builtin_amdgcn_mfma_f32_16x16x32_f16(a00, b0, acc[0][nt], 0, 0, 0); \
                acc[1][nt] = __builtin_amdgcn_mfma_f32_16x16x32_f16(a10, b0, acc[1][nt], 0, 0, 0); \
                acc[0][nt] = __builtin_amdgcn_mfma_f32_16x16x32_f16(w2l, bm, acc[0][nt], 0, 0, 0); \
                acc[1][nt] = __builtin_amdgcn_mfma_f32_16x16x32_f16(w2h, bm, acc[1][nt], 0, 0, 0); \
                ac3[0][nt] = __builtin_amdgcn_mfma_f32_16x16x32_f16(w3l, b0, ac3[0][nt], 0, 0, 0); \
                ac3[1][nt] = __builtin_amdgcn_mfma_f32_16x16x32_f16(w3h, b0, ac3[1][nt], 0, 0, 0); \
            } \
        } \
    } while (0)

    // drain pre-loop VMEM (deg/delta loads) so counted vmcnt sees only stages
    asm volatile("s_waitcnt vmcnt(0)" ::: "memory");
    STAGE(0, 0);
    #pragma unroll
    for (int ki = 0; ki < 20; ki++) {
        int cb = ki & 1, nb = cb ^ 1;
        if (ki < 19) STAGE(ki + 1, nb);
        // wait for CURRENT tile's loads only; next tile's stay in flight
        if (ki == 19)        asm volatile("s_waitcnt vmcnt(0)" ::: "memory");
        else if (ki + 1 < 4) asm volatile("s_waitcnt vmcnt(4)" ::: "memory");
        else                 asm volatile("s_waitcnt vmcnt(8)" ::: "memory");
        asm volatile("s_barrier" ::: "memory");
        __builtin_amdgcn_s_setprio(1);
        COMPUTE(ki, cb);
        __builtin_amdgcn_s_setprio(0);
        asm volatile("s_barrier" ::: "memory");
    }
    #undef STAGE
    #undef COMPUTE

    // D[row=(lane>>4)*4+reg][col=lane&15]; row -> j, col -> node
    int rowq = q4 * 4;
    #pragma unroll
    for (int nt = 0; nt < 8; nt++) {
        int node = n0 + nt * 16 + col;
        float at = atv[nt];
        #pragma unroll
        for (int mt = 0; mt < 2; mt++) {
            int jb = w * 32 + mt * 16 + rowq;
            f32x4 v = acc[mt][nt], v3 = ac3[mt][nt];
            ushort4 o;
            o.x = f2h(fmaxf(v.x + at * v3.x + bias[jb], 0.0f));
            o.y = f2h(fmaxf(v.y + at * v3.y + bias[jb + 1], 0.0f));
            o.z = f2h(fmaxf(v.z + at * v3.z + bias[jb + 2], 0.0f));
            o.w = f2h(fmaxf(v.w + at * v3.w + bias[jb + 3], 0.0f));
            *(ushort4*)&hout[(size_t)node * D_HIDC + jb] = o;
        }
    }
}

// ---------------- epilogue kernels ----------------

__global__ void __launch_bounds__(256) k_pool(
        const u16* __restrict__ h, const int* __restrict__ goff,
        float* __restrict__ pooled) {
    __shared__ float sm[256];
    int g = blockIdx.x >> 2, s = blockIdx.x & 3;
    int gb = goff[g], ge = goff[g + 1];
    int len = ge - gb;
    int q = (len + 3) >> 2;
    int nb = gb + s * q;
    int ne = min(nb + q, ge);
    int t = threadIdx.x;
    int j = t & 127, half = t >> 7;
    float acc = 0.0f;
    for (int n = nb + half; n < ne; n += 2)
        acc += h2f(h[(size_t)n * D_HIDC + j]);
    sm[t] = acc; __syncthreads();
    if (t < 128) {
        float v = sm[t] + sm[t + 128];
        atomicAdd(&pooled[g * D_HIDC + j], v);
    }
}

// one block per graph; redundant mu/var recompute (pooled is tiny, L2-hot)
__global__ void __launch_bounds__(128) k_bn_fc(
        const float* __restrict__ pooled, const float* __restrict__ gamma,
        const float* __restrict__ beta, const float* __restrict__ fcW,
        const float* __restrict__ fcb, float* __restrict__ out) {
    __shared__ float bn[D_HIDC];
    int g = blockIdx.x, t = threadIdx.x;
    float s = 0.f, q = 0.f;
    for (int gg = 0; gg < N_GRAPHSC; gg++) {
        float v = pooled[gg * D_HIDC + t];
        s += v; q += v * v;
    }
    float mu = s * (1.0f / N_GRAPHSC);
    float var = q * (1.0f / N_GRAPHSC) - mu * mu;
    float inv = 1.0f / sqrtf(var + 1e-5f);
    bn[t] = (pooled[g * D_HIDC + t] - mu) * inv * gamma[t] + beta[t];
    __syncthreads();
    if (t < D_LATC) {
        float accum = fcb[t];
        for (int j = 0; j < D_HIDC; j++) accum += bn[j] * fcW[j * D_LATC + t];
        out[g * D_LATC + t] = accum;
    }
}

// ---------------- launch ----------------

extern "C" void kernel_launch(void* const* d_in, const int* in_sizes, int n_in,
                              void* d_out, int out_size, void* d_ws, size_t ws_size,
                              hipStream_t stream) {
    const float* x     = (const float*)d_in[0];
    const int*   ei    = (const int*)d_in[1];
    const int*   batch = (const int*)d_in[2];
    const float* W0 = (const float*)d_in[3];
    const float* b0 = (const float*)d_in[4];
    const float* W1 = (const float*)d_in[5];
    const float* b1 = (const float*)d_in[6];
    const float* W2 = (const float*)d_in[7];
    const float* b2 = (const float*)d_in[8];
    const float* gamma = (const float*)d_in[9];
    const float* beta  = (const float*)d_in[10];
    const float* fcW   = (const float*)d_in[11];
    const float* fcb   = (const float*)d_in[12];
    float* out = (float*)d_out;
    const int* srcv = ei;
    const int* dstv = ei + N_EDGESC;

    char* p = (char*)d_ws;
    auto alloc = [&](size_t bytes) -> char* {
        char* r = p;
        p += (bytes + 255) & ~(size_t)255;
        return r;
    };
    int*   deg_cnt = (int*)alloc((size_t)N_PAD * 4);
    int*   cursor  = (int*)alloc((size_t)N_NODESC * 4);
    float* delta_p = (float*)alloc(4);
    float* pooled  = (float*)alloc((size_t)N_GRAPHSC * D_HIDC * 4);
    char*  zero_end = p;
    int*   row_off = (int*)alloc((size_t)(N_NODESC + 1) * 4);
    int*   goff    = (int*)alloc((size_t)(N_GRAPHSC + 1) * 4);
    int*   bsum    = (int*)alloc(256 * 4);
    float* lsum    = (float*)alloc(256 * 4);
    int*   csr_src = (int*)alloc((size_t)N_EDGESC * 4);
    u16*   Wt      = (u16*)alloc((size_t)3 * D_WROW * D_HIDC * 2);   // 1.28 MB
    u16*   hA      = (u16*)alloc((size_t)N_PAD * D_HIDC * 2);        // 12.8 MB
    u16*   hB      = (u16*)alloc((size_t)N_PAD * D_HIDC * 2);        // 12.8 MB
    u16*   G       = (u16*)alloc((size_t)N_PAD * D_GS * 2);          // 51.2 MB

    int nz = (int)((zero_end - (char*)deg_cnt) / 4);
    int ZB = (nz + 255) / 256;
    int setup_grid = ZB + 12500 + 2496 + 1;
    k_setup<<<setup_grid, 256, 0, stream>>>(x, W0, W1, W2, batch,
                                            hB, Wt, deg_cnt, nz, ZB, goff);
    k_count<<<(N_EDGESC + 255) / 256, 256, 0, stream>>>(dstv, deg_cnt);
    k_scan_part<<<196, 256, 0, stream>>>(deg_cnt, bsum, lsum);
    k_scan_block<<<1, 256, 0, stream>>>(bsum, lsum, delta_p);
    k_scan_final<<<196, 256, 0, stream>>>(deg_cnt, bsum, row_off);
    k_fill_csr<<<(N_EDGESC + 255) / 256, 256, 0, stream>>>(srcv, dstv, row_off, cursor, csr_src);

    const float* bs[3] = {b0, b1, b2};
    const u16* h_in[3]  = {hB, hA, hB};
    u16*       h_out[3] = {hA, hB, hA};
    size_t wsz = (size_t)D_WROW * D_HIDC;
    for (int l = 0; l < 3; l++) {
        k_aggregate<<<(N_NODESC + 3) / 4, 256, 0, stream>>>(
            h_in[l], row_off, csr_src, G);
        k_gemm<<<N_PAD / 128, 256, 0, stream>>>(
            h_in[l], G, Wt + (size_t)l * wsz, deg_cnt, delta_p, bs[l], h_out[l]);
    }
    k_pool<<<4 * N_GRAPHSC, 256, 0, stream>>>(h_out[2], goff, pooled);
    k_bn_fc<<<N_GRAPHSC, 128, 0, stream>>>(pooled, gamma, beta, fcW, fcb, out);
}

// Round 6
// 386.918 us; speedup vs baseline: 1.0430x; 1.0430x over previous
//
#include <hip/hip_runtime.h>
#include <cstdint>
#include <cstddef>

#define N_NODESC 50000
#define N_PAD    50048   // 391 * 128
#define N_EDGESC 600000
#define N_GRAPHSC 64
#define D_HIDC   128
#define D_LATC   64
#define D_GS     512     // G = [mean, max, min, std] (h section read from h directly)
#define D_WROW   1664    // transposed W row length (13*128)

typedef unsigned short u16;
typedef unsigned int   u32;

typedef _Float16 f16x8 __attribute__((ext_vector_type(8)));
typedef _Float16 f16x2 __attribute__((ext_vector_type(2)));
typedef __fp16   hh2   __attribute__((ext_vector_type(2)));
typedef float    f32x4 __attribute__((ext_vector_type(4)));
typedef float    f32x2 __attribute__((ext_vector_type(2)));

__device__ __forceinline__ u16 f2h(float f) {
    return __builtin_bit_cast(u16, (_Float16)f);
}
__device__ __forceinline__ float h2f(u16 u) {
    return (float)__builtin_bit_cast(_Float16, u);
}
__device__ __forceinline__ u32 pkrtz(float a, float b) {
    return __builtin_bit_cast(u32, __builtin_amdgcn_cvt_pkrtz(a, b));
}

// packed f32 ops (force v_pk_* codegen; pure-VALU asm, no ordering hazard)
__device__ __forceinline__ f32x2 pk_add(f32x2 a, f32x2 b) {
    f32x2 d;
    asm("v_pk_add_f32 %0, %1, %2" : "=v"(d) : "v"(a), "v"(b));
    return d;
}
__device__ __forceinline__ f32x2 pk_fma(f32x2 a, f32x2 b, f32x2 c) {
    f32x2 d;
    asm("v_pk_fma_f32 %0, %1, %2, %3" : "=v"(d) : "v"(a), "v"(b), "v"(c));
    return d;
}

__device__ __forceinline__ void gll16(void* lds, const void* g) {
    // async global->LDS, 16B per lane; HW dest = wave-uniform base + lane*16
    __builtin_amdgcn_global_load_lds(
        (const __attribute__((address_space(1))) void*)g,
        (__attribute__((address_space(3))) void*)lds, 16, 0, 0);
}

// ---------------- fused setup ----------------
// block ranges: [0,ZB) zero | [ZB,ZB+12500) x2h | next 2496 wconv | last goff
__global__ void __launch_bounds__(256) k_setup(
        const float* __restrict__ x, const float* __restrict__ W0,
        const float* __restrict__ W1, const float* __restrict__ W2,
        const int* __restrict__ batch,
        u16* __restrict__ h, u16* __restrict__ Wt,
        int* __restrict__ zero_base, int nz, int ZB, int* __restrict__ goff) {
    int b = blockIdx.x;
    int t = threadIdx.x;
    if (b < ZB) {
        int i = b * 256 + t;
        if (i < nz) zero_base[i] = 0;
        return;
    }
    b -= ZB;
    if (b < 12500) {                       // x -> fp16 (2 elems/thread)
        int i = b * 256 + t;
        float2 v = ((const float2*)x)[i];
        ((u32*)h)[i] = (u32)f2h(v.x) | ((u32)f2h(v.y) << 16);
        return;
    }
    b -= 12500;
    if (b < 2496) {                        // W transpose+cast: [1664][128] -> [128][1664]
        int which = b / 832;
        int i = (b % 832) * 256 + t;
        const float* W = (which == 0) ? W0 : (which == 1) ? W1 : W2;
        int k = i / D_HIDC, j = i % D_HIDC;
        Wt[(size_t)which * D_WROW * D_HIDC + (size_t)j * D_WROW + k] = f2h(W[i]);
        return;
    }
    // goff via binary search over sorted batch
    int g = t;
    if (g <= N_GRAPHSC) {
        int lo = 0, hi = N_NODESC;
        while (lo < hi) {
            int mid = (lo + hi) >> 1;
            if (batch[mid] < g) lo = mid + 1; else hi = mid;
        }
        goff[g] = lo;
    }
}

__global__ void k_count(const int* __restrict__ dst, int* __restrict__ deg) {
    int e = blockIdx.x * 256 + threadIdx.x;
    if (e < N_EDGESC) atomicAdd(&deg[dst[e]], 1);
}

// 196 blocks: per-block int sum -> bsum, per-block logf sum -> lsum
__global__ void __launch_bounds__(256) k_scan_part(
        const int* __restrict__ deg, int* __restrict__ bsum,
        float* __restrict__ lsum) {
    __shared__ int s[256];
    __shared__ float ls[256];
    int idx = blockIdx.x * 256 + threadIdx.x;
    int v = (idx < N_NODESC) ? deg[idx] : 0;
    s[threadIdx.x] = v;
    ls[threadIdx.x] = (idx < N_NODESC) ? logf((float)v + 1.0f) : 0.0f;
    __syncthreads();
    for (int o = 128; o > 0; o >>= 1) {
        if (threadIdx.x < o) {
            s[threadIdx.x] += s[threadIdx.x + o];
            ls[threadIdx.x] += ls[threadIdx.x + o];
        }
        __syncthreads();
    }
    if (threadIdx.x == 0) { bsum[blockIdx.x] = s[0]; lsum[blockIdx.x] = ls[0]; }
}

// 1 block: exclusive-scan bsum (196 entries) + reduce lsum -> delta
__global__ void __launch_bounds__(256) k_scan_block(
        int* __restrict__ bsum, const float* __restrict__ lsum,
        float* __restrict__ delta_p) {
    __shared__ int s[256];
    __shared__ float ls[256];
    int t = threadIdx.x;
    int v = (t < 196) ? bsum[t] : 0;
    s[t] = v;
    ls[t] = (t < 196) ? lsum[t] : 0.0f;
    __syncthreads();
    for (int o = 1; o < 256; o <<= 1) {
        int add = (t >= o) ? s[t - o] : 0;
        __syncthreads();
        s[t] += add;
        __syncthreads();
    }
    if (t < 196) bsum[t] = s[t] - v;   // exclusive
    for (int o = 128; o > 0; o >>= 1) {
        if (t < o) ls[t] += ls[t + o];
        __syncthreads();
    }
    if (t == 0) delta_p[0] = ls[0] * (1.0f / (float)N_NODESC);
}

// 196 blocks: block-local exclusive scan + block offset -> row_off
__global__ void __launch_bounds__(256) k_scan_final(
        const int* __restrict__ deg, const int* __restrict__ bsum,
        int* __restrict__ row_off) {
    __shared__ int s[256];
    int t = threadIdx.x;
    int idx = blockIdx.x * 256 + t;
    int v = (idx < N_NODESC) ? deg[idx] : 0;
    s[t] = v; __syncthreads();
    for (int o = 1; o < 256; o <<= 1) {
        int add = (t >= o) ? s[t - o] : 0;
        __syncthreads();
        s[t] += add;
        __syncthreads();
    }
    int excl = s[t] - v + bsum[blockIdx.x];
    if (idx < N_NODESC) row_off[idx] = excl;
    if (idx == 0) row_off[N_NODESC] = N_EDGESC;
}

// csr stores PRE-SCALED byte offsets (src*256) so gathers are base+u32 voffset
__global__ void k_fill_csr(const int* __restrict__ src, const int* __restrict__ dst,
                           const int* __restrict__ row_off, int* __restrict__ cursor,
                           int* __restrict__ csr_src) {
    int e = blockIdx.x * 256 + threadIdx.x;
    if (e < N_EDGESC) {
        int d = dst[e];
        int pos = row_off[d] + atomicAdd(&cursor[d], 1);
        csr_src[pos] = src[e] << 8;   // byte offset into h (128 * 2B per row)
    }
}

// ---------------- per-layer kernels ----------------

// R6: ONE NODE PER HALF-WAVE (wave = 2 nodes, block = 8). Each half owns all
// of its node's edges -> no cross-half shuffle merges; epilogue issue cost per
// node halves; per-wave prologue overhead halves. Differing trip counts between
// halves handled by exec-mask divergence (cost = max(degA,degB) ~ +18%).
// Epilogue: packed f32x2 mean/var, v_cvt_pkrtz packing, max/min stored as
// already-packed f16 bits (uniform d==0 zero-select), 4 uniform stores.
__global__ void __launch_bounds__(256) k_aggregate(
        const u16* __restrict__ h, const int* __restrict__ row_off,
        const int* __restrict__ csr_src, u16* __restrict__ G) {
    int lane = threadIdx.x & 63;
    int half = lane >> 5, l32 = lane & 31;
    int n = blockIdx.x * 8 + ((threadIdx.x >> 6) << 1) + half;
    if (n >= N_NODESC) return;
    int c4 = 4 * l32;
    u32 c8 = 8u * (u32)l32;
    const char* h8 = (const char*)h;
    int beg = row_off[n], end = row_off[n + 1];
    const _Float16 NEG = (_Float16)(-65504.0f), POS = (_Float16)(65504.0f);
    f32x2 s01 = {0.f, 0.f}, s23 = {0.f, 0.f};
    f32x2 q01 = {0.f, 0.f}, q23 = {0.f, 0.f};
    f16x2 mx01 = {NEG, NEG}, mx23 = {NEG, NEG};
    f16x2 mn01 = {POS, POS}, mn23 = {POS, POS};

    #define PROC(u) { \
        f16x2 p01 = __builtin_bit_cast(f16x2, (u).x); \
        f16x2 p23 = __builtin_bit_cast(f16x2, (u).y); \
        f32x2 c01 = __builtin_convertvector(p01, f32x2); \
        f32x2 c23 = __builtin_convertvector(p23, f32x2); \
        s01 = pk_add(s01, c01); s23 = pk_add(s23, c23); \
        q01 = pk_fma(c01, c01, q01); q23 = pk_fma(c23, c23, q23); \
        mx01 = __builtin_elementwise_max(mx01, p01); \
        mx23 = __builtin_elementwise_max(mx23, p23); \
        mn01 = __builtin_elementwise_min(mn01, p01); \
        mn23 = __builtin_elementwise_min(mn23, p23); }

    int i = beg;
    for (; i + 3 < end; i += 4) {
        u32 e0 = (u32)csr_src[i],     e1 = (u32)csr_src[i + 1];
        u32 e2 = (u32)csr_src[i + 2], e3 = (u32)csr_src[i + 3];
        uint2 u0 = *(const uint2*)(h8 + (e0 + c8));
        uint2 u1 = *(const uint2*)(h8 + (e1 + c8));
        uint2 u2 = *(const uint2*)(h8 + (e2 + c8));
        uint2 u3 = *(const uint2*)(h8 + (e3 + c8));
        PROC(u0); PROC(u1); PROC(u2); PROC(u3);
    }
    for (; i < end; ++i) {
        u32 e0 = (u32)csr_src[i];
        uint2 u0 = *(const uint2*)(h8 + (e0 + c8));
        PROC(u0);
    }
    #undef PROC

    int d = end - beg;
    float inv = 1.0f / fmaxf((float)d, 1.0f);
    f32x2 vinv = {inv, inv};
    f32x2 me01 = s01 * vinv, me23 = s23 * vinv;
    f32x2 qn01 = q01 * vinv, qn23 = q23 * vinv;
    f32x2 var01 = qn01 - me01 * me01;
    f32x2 var23 = qn23 - me23 * me23;
    const f32x2 z2 = {0.f, 0.f};
    var01 = __builtin_elementwise_max(var01, z2);
    var23 = __builtin_elementwise_max(var23, z2);
    float sd0 = sqrtf(var01.x + 1e-5f), sd1 = sqrtf(var01.y + 1e-5f);
    float sd2 = sqrtf(var23.x + 1e-5f), sd3 = sqrtf(var23.y + 1e-5f);

    u32 mep01 = pkrtz(me01.x, me01.y), mep23 = pkrtz(me23.x, me23.y);
    u32 sdp01 = pkrtz(sd0, sd1),       sdp23 = pkrtz(sd2, sd3);
    u32 mxb01 = __builtin_bit_cast(u32, mx01), mxb23 = __builtin_bit_cast(u32, mx23);
    u32 mnb01 = __builtin_bit_cast(u32, mn01), mnb23 = __builtin_bit_cast(u32, mn23);
    if (d == 0) { mxb01 = mxb23 = mnb01 = mnb23 = 0u; }

    u16* base = G + (size_t)n * D_GS;
    uint2 M; M.x = mep01; M.y = mep23;
    uint2 X; X.x = mxb01; X.y = mxb23;
    uint2 N_; N_.x = mnb01; N_.y = mnb23;
    uint2 S; S.x = sdp01; S.y = sdp23;
    *(uint2*)(base + c4)       = M;
    *(uint2*)(base + 128 + c4) = X;
    *(uint2*)(base + 256 + c4) = N_;
    *(uint2*)(base + 384 + c4) = S;
}

// h_out[n][j] = relu(bias + B*W1 + am*(S*W2) + at*(S*W3)) over logical B = [h|G]
// R4 structure (verified best: all-LDS gll16 staging, 2-barrier, 128 nodes/block,
// 2 blocks/CU; R5's counted-vmcnt BK=32 pipeline regressed -7us -> reverted).
// ki<2 B-tiles staged from h directly; ki>=2 from the 512-col G at (k0-128).
__global__ void __launch_bounds__(256, 2) k_gemm(
        const u16* __restrict__ hin, const u16* __restrict__ G,
        const u16* __restrict__ Wt,
        const int* __restrict__ deg, const float* __restrict__ delta_p,
        const float* __restrict__ bias, u16* __restrict__ hout) {
    __shared__ _Float16 A1[128 * 64];   // 16 KB (W1)
    __shared__ _Float16 A2[128 * 64];   // 16 KB (W2)
    __shared__ _Float16 A3[128 * 64];   // 16 KB (W3)
    __shared__ _Float16 Bt[128 * 64];   // 16 KB (128-node B tile)
    const _Float16* Wf = (const _Float16*)Wt;
    const _Float16* Gf = (const _Float16*)G;
    const _Float16* Hf = (const _Float16*)hin;
    int n0 = blockIdx.x * 128;
    int t = threadIdx.x;
    int w = t >> 6, lane = t & 63;
    int srow8 = lane >> 3, sslot = lane & 7;
    int stg = (sslot ^ srow8) * 8;        // swizzled source chunk offset
    int q4 = lane >> 4, r16 = lane & 15;
    int sx0 = (q4 ^ (lane & 7)) * 8;
    int sx1 = ((q4 + 4) ^ (lane & 7)) * 8;
    int col = lane & 15;

    float delta = delta_p[0];
    float atv[8];
    _Float16 amh[8];
    #pragma unroll
    for (int nt = 0; nt < 8; nt++) {
        int node = n0 + nt * 16 + col;
        float logd = logf((float)deg[node] + 1.0f);
        amh[nt] = (_Float16)(logd / delta);
        atv[nt] = delta / fmaxf(logd, 1e-5f);
    }

    f32x4 acc[2][8], ac3[2][8];
    #pragma unroll
    for (int a = 0; a < 2; a++)
        #pragma unroll
        for (int b = 0; b < 8; b++) {
            acc[a][b] = (f32x4){0.f, 0.f, 0.f, 0.f};
            ac3[a][b] = (f32x4){0.f, 0.f, 0.f, 0.f};
        }

    for (int ki = 0; ki < 10; ki++) {
        int k0 = ki * 64;
        bool sreg = (k0 >= 128);
        __syncthreads();
        #pragma unroll
        for (int r = 0; r < 4; r++) {
            int rr = r * 4 + w;
            const _Float16* wrow = Wf + (size_t)(rr * 8 + srow8) * D_WROW;
            gll16(&A1[rr * 512], wrow + k0 + stg);
        }
        if (sreg) {
            #pragma unroll
            for (int r = 0; r < 4; r++) {
                int rr = r * 4 + w;
                const _Float16* wrow = Wf + (size_t)(rr * 8 + srow8) * D_WROW;
                gll16(&A2[rr * 512], wrow + 512 + k0 + stg);
                gll16(&A3[rr * 512], wrow + 1024 + k0 + stg);
            }
        }
        #pragma unroll
        for (int q = 0; q < 4; q++) {
            int rr = q * 4 + w;
            int row = n0 + rr * 8 + srow8;
            const _Float16* bsrc = (!sreg)
                ? Hf + (size_t)row * D_HIDC + k0 + stg
                : Gf + (size_t)row * D_GS + (k0 - 128) + stg;
            gll16(&Bt[rr * 512], bsrc);
        }
        __syncthreads();
        f16x8 a00 = *(const f16x8*)&A1[(w * 32 + r16) * 64 + sx0];
        f16x8 a01 = *(const f16x8*)&A1[(w * 32 + r16) * 64 + sx1];
        f16x8 a10 = *(const f16x8*)&A1[(w * 32 + 16 + r16) * 64 + sx0];
        f16x8 a11 = *(const f16x8*)&A1[(w * 32 + 16 + r16) * 64 + sx1];
        if (!sreg) {
            #pragma unroll
            for (int nt = 0; nt < 8; nt++) {
                f16x8 b0 = *(const f16x8*)&Bt[(nt * 16 + r16) * 64 + sx0];
                f16x8 b1 = *(const f16x8*)&Bt[(nt * 16 + r16) * 64 + sx1];
                acc[0][nt] = __builtin_amdgcn_mfma_f32_16x16x32_f16(a00, b0, acc[0][nt], 0, 0, 0);
                acc[1][nt] = __builtin_amdgcn_mfma_f32_16x16x32_f16(a10, b0, acc[1][nt], 0, 0, 0);
                acc[0][nt] = __builtin_amdgcn_mfma_f32_16x16x32_f16(a01, b1, acc[0][nt], 0, 0, 0);
                acc[1][nt] = __builtin_amdgcn_mfma_f32_16x16x32_f16(a11, b1, acc[1][nt], 0, 0, 0);
            }
        } else {
            f16x8 w2a0 = *(const f16x8*)&A2[(w * 32 + r16) * 64 + sx0];
            f16x8 w2a1 = *(const f16x8*)&A2[(w * 32 + r16) * 64 + sx1];
            f16x8 w2b0 = *(const f16x8*)&A2[(w * 32 + 16 + r16) * 64 + sx0];
            f16x8 w2b1 = *(const f16x8*)&A2[(w * 32 + 16 + r16) * 64 + sx1];
            f16x8 w3a0 = *(const f16x8*)&A3[(w * 32 + r16) * 64 + sx0];
            f16x8 w3a1 = *(const f16x8*)&A3[(w * 32 + r16) * 64 + sx1];
            f16x8 w3b0 = *(const f16x8*)&A3[(w * 32 + 16 + r16) * 64 + sx0];
            f16x8 w3b1 = *(const f16x8*)&A3[(w * 32 + 16 + r16) * 64 + sx1];
            #pragma unroll
            for (int nt = 0; nt < 8; nt++) {
                f16x8 b0 = *(const f16x8*)&Bt[(nt * 16 + r16) * 64 + sx0];
                f16x8 b1 = *(const f16x8*)&Bt[(nt * 16 + r16) * 64 + sx1];
                f16x8 bm0 = b0 * amh[nt];
                f16x8 bm1 = b1 * amh[nt];
                acc[0][nt] = __builtin_amdgcn_mfma_f32_16x16x32_f16(a00, b0, acc[0][nt], 0, 0, 0);
                acc[1][nt] = __builtin_amdgcn_mfma_f32_16x16x32_f16(a10, b0, acc[1][nt], 0, 0, 0);
                acc[0][nt] = __builtin_amdgcn_mfma_f32_16x16x32_f16(a01, b1, acc[0][nt], 0, 0, 0);
                acc[1][nt] = __builtin_amdgcn_mfma_f32_16x16x32_f16(a11, b1, acc[1][nt], 0, 0, 0);
                acc[0][nt] = __builtin_amdgcn_mfma_f32_16x16x32_f16(w2a0, bm0, acc[0][nt], 0, 0, 0);
                acc[1][nt] = __builtin_amdgcn_mfma_f32_16x16x32_f16(w2b0, bm0, acc[1][nt], 0, 0, 0);
                acc[0][nt] = __builtin_amdgcn_mfma_f32_16x16x32_f16(w2a1, bm1, acc[0][nt], 0, 0, 0);
                acc[1][nt] = __builtin_amdgcn_mfma_f32_16x16x32_f16(w2b1, bm1, acc[1][nt], 0, 0, 0);
                ac3[0][nt] = __builtin_amdgcn_mfma_f32_16x16x32_f16(w3a0, b0, ac3[0][nt], 0, 0, 0);
                ac3[1][nt] = __builtin_amdgcn_mfma_f32_16x16x32_f16(w3b0, b0, ac3[1][nt], 0, 0, 0);
                ac3[0][nt] = __builtin_amdgcn_mfma_f32_16x16x32_f16(w3a1, b1, ac3[0][nt], 0, 0, 0);
                ac3[1][nt] = __builtin_amdgcn_mfma_f32_16x16x32_f16(w3b1, b1, ac3[1][nt], 0, 0, 0);
            }
        }
    }
    // D[row=(lane>>4)*4+reg][col=lane&15]; row -> j, col -> node
    int rowq = q4 * 4;
    #pragma unroll
    for (int nt = 0; nt < 8; nt++) {
        int node = n0 + nt * 16 + col;
        float at = atv[nt];
        #pragma unroll
        for (int mt = 0; mt < 2; mt++) {
            int jb = w * 32 + mt * 16 + rowq;
            f32x4 v = acc[mt][nt], v3 = ac3[mt][nt];
            ushort4 o;
            o.x = f2h(fmaxf(v.x + at * v3.x + bias[jb], 0.0f));
            o.y = f2h(fmaxf(v.y + at * v3.y + bias[jb + 1], 0.0f));
            o.z = f2h(fmaxf(v.z + at * v3.z + bias[jb + 2], 0.0f));
            o.w = f2h(fmaxf(v.w + at * v3.w + bias[jb + 3], 0.0f));
            *(ushort4*)&hout[(size_t)node * D_HIDC + jb] = o;
        }
    }
}

// ---------------- epilogue kernels ----------------

__global__ void __launch_bounds__(256) k_pool(
        const u16* __restrict__ h, const int* __restrict__ goff,
        float* __restrict__ pooled) {
    __shared__ float sm[256];
    int g = blockIdx.x >> 2, s = blockIdx.x & 3;
    int gb = goff[g], ge = goff[g + 1];
    int len = ge - gb;
    int q = (len + 3) >> 2;
    int nb = gb + s * q;
    int ne = min(nb + q, ge);
    int t = threadIdx.x;
    int j = t & 127, half = t >> 7;
    float acc = 0.0f;
    for (int n = nb + half; n < ne; n += 2)
        acc += h2f(h[(size_t)n * D_HIDC + j]);
    sm[t] = acc; __syncthreads();
    if (t < 128) {
        float v = sm[t] + sm[t + 128];
        atomicAdd(&pooled[g * D_HIDC + j], v);
    }
}

// one block per graph; redundant mu/var recompute (pooled is tiny, L2-hot)
__global__ void __launch_bounds__(128) k_bn_fc(
        const float* __restrict__ pooled, const float* __restrict__ gamma,
        const float* __restrict__ beta, const float* __restrict__ fcW,
        const float* __restrict__ fcb, float* __restrict__ out) {
    __shared__ float bn[D_HIDC];
    int g = blockIdx.x, t = threadIdx.x;
    float s = 0.f, q = 0.f;
    for (int gg = 0; gg < N_GRAPHSC; gg++) {
        float v = pooled[gg * D_HIDC + t];
        s += v; q += v * v;
    }
    float mu = s * (1.0f / N_GRAPHSC);
    float var = q * (1.0f / N_GRAPHSC) - mu * mu;
    float inv = 1.0f / sqrtf(var + 1e-5f);
    bn[t] = (pooled[g * D_HIDC + t] - mu) * inv * gamma[t] + beta[t];
    __syncthreads();
    if (t < D_LATC) {
        float accum = fcb[t];
        for (int j = 0; j < D_HIDC; j++) accum += bn[j] * fcW[j * D_LATC + t];
        out[g * D_LATC + t] = accum;
    }
}

// ---------------- launch ----------------

extern "C" void kernel_launch(void* const* d_in, const int* in_sizes, int n_in,
                              void* d_out, int out_size, void* d_ws, size_t ws_size,
                              hipStream_t stream) {
    const float* x     = (const float*)d_in[0];
    const int*   ei    = (const int*)d_in[1];
    const int*   batch = (const int*)d_in[2];
    const float* W0 = (const float*)d_in[3];
    const float* b0 = (const float*)d_in[4];
    const float* W1 = (const float*)d_in[5];
    const float* b1 = (const float*)d_in[6];
    const float* W2 = (const float*)d_in[7];
    const float* b2 = (const float*)d_in[8];
    const float* gamma = (const float*)d_in[9];
    const float* beta  = (const float*)d_in[10];
    const float* fcW   = (const float*)d_in[11];
    const float* fcb   = (const float*)d_in[12];
    float* out = (float*)d_out;
    const int* srcv = ei;
    const int* dstv = ei + N_EDGESC;

    char* p = (char*)d_ws;
    auto alloc = [&](size_t bytes) -> char* {
        char* r = p;
        p += (bytes + 255) & ~(size_t)255;
        return r;
    };
    int*   deg_cnt = (int*)alloc((size_t)N_PAD * 4);
    int*   cursor  = (int*)alloc((size_t)N_NODESC * 4);
    float* delta_p = (float*)alloc(4);
    float* pooled  = (float*)alloc((size_t)N_GRAPHSC * D_HIDC * 4);
    char*  zero_end = p;
    int*   row_off = (int*)alloc((size_t)(N_NODESC + 1) * 4);
    int*   goff    = (int*)alloc((size_t)(N_GRAPHSC + 1) * 4);
    int*   bsum    = (int*)alloc(256 * 4);
    float* lsum    = (float*)alloc(256 * 4);
    int*   csr_src = (int*)alloc((size_t)N_EDGESC * 4);
    u16*   Wt      = (u16*)alloc((size_t)3 * D_WROW * D_HIDC * 2);   // 1.28 MB
    u16*   hA      = (u16*)alloc((size_t)N_PAD * D_HIDC * 2);        // 12.8 MB
    u16*   hB      = (u16*)alloc((size_t)N_PAD * D_HIDC * 2);        // 12.8 MB
    u16*   G       = (u16*)alloc((size_t)N_PAD * D_GS * 2);          // 51.2 MB

    int nz = (int)((zero_end - (char*)deg_cnt) / 4);
    int ZB = (nz + 255) / 256;
    int setup_grid = ZB + 12500 + 2496 + 1;
    k_setup<<<setup_grid, 256, 0, stream>>>(x, W0, W1, W2, batch,
                                            hB, Wt, deg_cnt, nz, ZB, goff);
    k_count<<<(N_EDGESC + 255) / 256, 256, 0, stream>>>(dstv, deg_cnt);
    k_scan_part<<<196, 256, 0, stream>>>(deg_cnt, bsum, lsum);
    k_scan_block<<<1, 256, 0, stream>>>(bsum, lsum, delta_p);
    k_scan_final<<<196, 256, 0, stream>>>(deg_cnt, bsum, row_off);
    k_fill_csr<<<(N_EDGESC + 255) / 256, 256, 0, stream>>>(srcv, dstv, row_off, cursor, csr_src);

    const float* bs[3] = {b0, b1, b2};
    const u16* h_in[3]  = {hB, hA, hB};
    u16*       h_out[3] = {hA, hB, hA};
    size_t wsz = (size_t)D_WROW * D_HIDC;
    for (int l = 0; l < 3; l++) {
        k_aggregate<<<(N_NODESC + 7) / 8, 256, 0, stream>>>(
            h_in[l], row_off, csr_src, G);
        k_gemm<<<N_PAD / 128, 256, 0, stream>>>(
            h_in[l], G, Wt + (size_t)l * wsz, deg_cnt, delta_p, bs[l], h_out[l]);
    }
    k_pool<<<4 * N_GRAPHSC, 256, 0, stream>>>(h_out[2], goff, pooled);
    k_bn_fc<<<N_GRAPHSC, 128, 0, stream>>>(pooled, gamma, beta, fcW, fcb, out);
}

// Round 7
// 378.506 us; speedup vs baseline: 1.0662x; 1.0222x over previous
//
#include <hip/hip_runtime.h>
#include <cstdint>
#include <cstddef>

#define N_NODESC 50000
#define N_PAD    50048   // 391 * 128
#define N_EDGESC 600000
#define N_GRAPHSC 64
#define D_HIDC   128
#define D_LATC   64
#define D_GS     512     // G = [mean, max, min, std] (h section read from h directly)
#define D_WROW   1664    // transposed W row length (13*128)

typedef unsigned short u16;
typedef unsigned int   u32;

typedef _Float16 f16x8 __attribute__((ext_vector_type(8)));
typedef _Float16 f16x2 __attribute__((ext_vector_type(2)));
typedef float    f32x4 __attribute__((ext_vector_type(4)));
typedef float    f32x2 __attribute__((ext_vector_type(2)));

__device__ __forceinline__ u16 f2h(float f) {
    return __builtin_bit_cast(u16, (_Float16)f);
}
__device__ __forceinline__ float h2f(u16 u) {
    return (float)__builtin_bit_cast(_Float16, u);
}
__device__ __forceinline__ u32 pkrtz(float a, float b) {
    return __builtin_bit_cast(u32, __builtin_amdgcn_cvt_pkrtz(a, b));
}

// packed f32 ops (force v_pk_* codegen; pure-VALU asm, no ordering hazard)
__device__ __forceinline__ f32x2 pk_add(f32x2 a, f32x2 b) {
    f32x2 d;
    asm("v_pk_add_f32 %0, %1, %2" : "=v"(d) : "v"(a), "v"(b));
    return d;
}
__device__ __forceinline__ f32x2 pk_fma(f32x2 a, f32x2 b, f32x2 c) {
    f32x2 d;
    asm("v_pk_fma_f32 %0, %1, %2, %3" : "=v"(d) : "v"(a), "v"(b), "v"(c));
    return d;
}

__device__ __forceinline__ void gll16(void* lds, const void* g) {
    // async global->LDS, 16B per lane; HW dest = wave-uniform base + lane*16
    __builtin_amdgcn_global_load_lds(
        (const __attribute__((address_space(1))) void*)g,
        (__attribute__((address_space(3))) void*)lds, 16, 0, 0);
}

// ---------------- fused setup ----------------
// block ranges: [0,ZB) zero | [ZB,ZB+12500) x2h | next 78 wconv(LDS) | last goff
// R7: LDS-tiled W transpose (78 blocks replace 2496). Old path: scattered 2B
// stores at 3.3KB stride = ~64x write amplification (~80 MB traffic for 1.28 MB
// of Wt). New: coalesced f32 reads -> 64x128 u16 LDS tile -> 4x16B contiguous
// stores per thread. Bank-check: read bank=(j>>1)%32, 2 lanes/bank = free.
__global__ void __launch_bounds__(256) k_setup(
        const float* __restrict__ x, const float* __restrict__ W0,
        const float* __restrict__ W1, const float* __restrict__ W2,
        const int* __restrict__ batch,
        u16* __restrict__ h, u16* __restrict__ Wt,
        int* __restrict__ zero_base, int nz, int ZB, int* __restrict__ goff) {
    __shared__ u16 lt[64 * 128];   // 16 KB transpose tile (wconv blocks only)
    int b = blockIdx.x;
    int t = threadIdx.x;
    if (b < ZB) {
        int i = b * 256 + t;
        if (i < nz) zero_base[i] = 0;
        return;
    }
    b -= ZB;
    if (b < 12500) {                       // x -> fp16 (2 elems/thread)
        int i = b * 256 + t;
        float2 v = ((const float2*)x)[i];
        ((u32*)h)[i] = (u32)f2h(v.x) | ((u32)f2h(v.y) << 16);
        return;
    }
    b -= 12500;
    if (b < 78) {                          // W transpose+cast, LDS-tiled
        int which = b / 26;
        int k0 = (b % 26) * 64;
        const float* W = (which == 0) ? W0 : (which == 1) ? W1 : W2;
        const float* src = W + (size_t)k0 * D_HIDC;
        for (int i = t; i < 64 * 128; i += 256)
            lt[i] = f2h(src[i]);           // lt[kk*128 + j]
        __syncthreads();
        int j = t & 127, kh = t >> 7;
        u16* dst = Wt + (size_t)which * D_WROW * D_HIDC
                      + (size_t)j * D_WROW + k0 + kh * 32;
        #pragma unroll
        for (int c = 0; c < 4; c++) {
            int kb = kh * 32 + c * 8;
            u32 p0 = (u32)lt[(kb + 0) * 128 + j] | ((u32)lt[(kb + 1) * 128 + j] << 16);
            u32 p1 = (u32)lt[(kb + 2) * 128 + j] | ((u32)lt[(kb + 3) * 128 + j] << 16);
            u32 p2 = (u32)lt[(kb + 4) * 128 + j] | ((u32)lt[(kb + 5) * 128 + j] << 16);
            u32 p3 = (u32)lt[(kb + 6) * 128 + j] | ((u32)lt[(kb + 7) * 128 + j] << 16);
            uint4 v; v.x = p0; v.y = p1; v.z = p2; v.w = p3;
            *(uint4*)(dst + c * 8) = v;
        }
        return;
    }
    // goff via binary search over sorted batch
    int g = t;
    if (g <= N_GRAPHSC) {
        int lo = 0, hi = N_NODESC;
        while (lo < hi) {
            int mid = (lo + hi) >> 1;
            if (batch[mid] < g) lo = mid + 1; else hi = mid;
        }
        goff[g] = lo;
    }
}

__global__ void k_count(const int* __restrict__ dst, int* __restrict__ deg) {
    int e = blockIdx.x * 256 + threadIdx.x;
    if (e < N_EDGESC) atomicAdd(&deg[dst[e]], 1);
}

// 196 blocks: per-block int sum -> bsum, per-block logf sum -> lsum
__global__ void __launch_bounds__(256) k_scan_part(
        const int* __restrict__ deg, int* __restrict__ bsum,
        float* __restrict__ lsum) {
    __shared__ int s[256];
    __shared__ float ls[256];
    int idx = blockIdx.x * 256 + threadIdx.x;
    int v = (idx < N_NODESC) ? deg[idx] : 0;
    s[threadIdx.x] = v;
    ls[threadIdx.x] = (idx < N_NODESC) ? logf((float)v + 1.0f) : 0.0f;
    __syncthreads();
    for (int o = 128; o > 0; o >>= 1) {
        if (threadIdx.x < o) {
            s[threadIdx.x] += s[threadIdx.x + o];
            ls[threadIdx.x] += ls[threadIdx.x + o];
        }
        __syncthreads();
    }
    if (threadIdx.x == 0) { bsum[blockIdx.x] = s[0]; lsum[blockIdx.x] = ls[0]; }
}

// 1 block: exclusive-scan bsum (196 entries) + reduce lsum -> delta
__global__ void __launch_bounds__(256) k_scan_block(
        int* __restrict__ bsum, const float* __restrict__ lsum,
        float* __restrict__ delta_p) {
    __shared__ int s[256];
    __shared__ float ls[256];
    int t = threadIdx.x;
    int v = (t < 196) ? bsum[t] : 0;
    s[t] = v;
    ls[t] = (t < 196) ? lsum[t] : 0.0f;
    __syncthreads();
    for (int o = 1; o < 256; o <<= 1) {
        int add = (t >= o) ? s[t - o] : 0;
        __syncthreads();
        s[t] += add;
        __syncthreads();
    }
    if (t < 196) bsum[t] = s[t] - v;   // exclusive
    for (int o = 128; o > 0; o >>= 1) {
        if (t < o) ls[t] += ls[t + o];
        __syncthreads();
    }
    if (t == 0) delta_p[0] = ls[0] * (1.0f / (float)N_NODESC);
}

// 196 blocks: block-local exclusive scan + block offset -> row_off
__global__ void __launch_bounds__(256) k_scan_final(
        const int* __restrict__ deg, const int* __restrict__ bsum,
        int* __restrict__ row_off) {
    __shared__ int s[256];
    int t = threadIdx.x;
    int idx = blockIdx.x * 256 + t;
    int v = (idx < N_NODESC) ? deg[idx] : 0;
    s[t] = v; __syncthreads();
    for (int o = 1; o < 256; o <<= 1) {
        int add = (t >= o) ? s[t - o] : 0;
        __syncthreads();
        s[t] += add;
        __syncthreads();
    }
    int excl = s[t] - v + bsum[blockIdx.x];
    if (idx < N_NODESC) row_off[idx] = excl;
    if (idx == 0) row_off[N_NODESC] = N_EDGESC;
}

// csr stores PRE-SCALED byte offsets (src*256) so gathers are base+u32 voffset
__global__ void k_fill_csr(const int* __restrict__ src, const int* __restrict__ dst,
                           const int* __restrict__ row_off, int* __restrict__ cursor,
                           int* __restrict__ csr_src) {
    int e = blockIdx.x * 256 + threadIdx.x;
    if (e < N_EDGESC) {
        int d = dst[e];
        int pos = row_off[d] + atomicAdd(&cursor[d], 1);
        csr_src[pos] = src[e] << 8;   // byte offset into h (128 * 2B per row)
    }
}

// ---------------- per-layer kernels ----------------

// R7: one node per half-wave (R6) + 8-deep gather pipeline with rotated index
// prefetch: issue 8 gathers on pre-loaded indices, immediately load next 8
// indices (independent -> overlap), then PROC. 4-wide stage for the tail.
__global__ void __launch_bounds__(256) k_aggregate(
        const u16* __restrict__ h, const int* __restrict__ row_off,
        const int* __restrict__ csr_src, u16* __restrict__ G) {
    int lane = threadIdx.x & 63;
    int half = lane >> 5, l32 = lane & 31;
    int n = blockIdx.x * 8 + ((threadIdx.x >> 6) << 1) + half;
    if (n >= N_NODESC) return;
    int c4 = 4 * l32;
    u32 c8 = 8u * (u32)l32;
    const char* h8 = (const char*)h;
    int beg = row_off[n], end = row_off[n + 1];
    const _Float16 NEG = (_Float16)(-65504.0f), POS = (_Float16)(65504.0f);
    f32x2 s01 = {0.f, 0.f}, s23 = {0.f, 0.f};
    f32x2 q01 = {0.f, 0.f}, q23 = {0.f, 0.f};
    f16x2 mx01 = {NEG, NEG}, mx23 = {NEG, NEG};
    f16x2 mn01 = {POS, POS}, mn23 = {POS, POS};

    #define PROC(u) { \
        f16x2 p01 = __builtin_bit_cast(f16x2, (u).x); \
        f16x2 p23 = __builtin_bit_cast(f16x2, (u).y); \
        f32x2 c01 = __builtin_convertvector(p01, f32x2); \
        f32x2 c23 = __builtin_convertvector(p23, f32x2); \
        s01 = pk_add(s01, c01); s23 = pk_add(s23, c23); \
        q01 = pk_fma(c01, c01, q01); q23 = pk_fma(c23, c23, q23); \
        mx01 = __builtin_elementwise_max(mx01, p01); \
        mx23 = __builtin_elementwise_max(mx23, p23); \
        mn01 = __builtin_elementwise_min(mn01, p01); \
        mn23 = __builtin_elementwise_min(mn23, p23); }
    #define GTH(e) (*(const uint2*)(h8 + ((e) + c8)))

    int i = beg;
    if (i + 8 <= end) {
        u32 e0 = (u32)csr_src[i],     e1 = (u32)csr_src[i + 1];
        u32 e2 = (u32)csr_src[i + 2], e3 = (u32)csr_src[i + 3];
        u32 e4 = (u32)csr_src[i + 4], e5 = (u32)csr_src[i + 5];
        u32 e6 = (u32)csr_src[i + 6], e7 = (u32)csr_src[i + 7];
        while (i + 16 <= end) {
            uint2 u0 = GTH(e0), u1 = GTH(e1), u2 = GTH(e2), u3 = GTH(e3);
            uint2 u4 = GTH(e4), u5 = GTH(e5), u6 = GTH(e6), u7 = GTH(e7);
            e0 = (u32)csr_src[i + 8];  e1 = (u32)csr_src[i + 9];
            e2 = (u32)csr_src[i + 10]; e3 = (u32)csr_src[i + 11];
            e4 = (u32)csr_src[i + 12]; e5 = (u32)csr_src[i + 13];
            e6 = (u32)csr_src[i + 14]; e7 = (u32)csr_src[i + 15];
            PROC(u0); PROC(u1); PROC(u2); PROC(u3);
            PROC(u4); PROC(u5); PROC(u6); PROC(u7);
            i += 8;
        }
        uint2 u0 = GTH(e0), u1 = GTH(e1), u2 = GTH(e2), u3 = GTH(e3);
        uint2 u4 = GTH(e4), u5 = GTH(e5), u6 = GTH(e6), u7 = GTH(e7);
        PROC(u0); PROC(u1); PROC(u2); PROC(u3);
        PROC(u4); PROC(u5); PROC(u6); PROC(u7);
        i += 8;
    }
    for (; i + 3 < end; i += 4) {
        u32 e0 = (u32)csr_src[i],     e1 = (u32)csr_src[i + 1];
        u32 e2 = (u32)csr_src[i + 2], e3 = (u32)csr_src[i + 3];
        uint2 u0 = GTH(e0), u1 = GTH(e1), u2 = GTH(e2), u3 = GTH(e3);
        PROC(u0); PROC(u1); PROC(u2); PROC(u3);
    }
    for (; i < end; ++i) {
        u32 e0 = (u32)csr_src[i];
        uint2 u0 = GTH(e0);
        PROC(u0);
    }
    #undef PROC
    #undef GTH

    int d = end - beg;
    float inv = 1.0f / fmaxf((float)d, 1.0f);
    f32x2 vinv = {inv, inv};
    f32x2 me01 = s01 * vinv, me23 = s23 * vinv;
    f32x2 qn01 = q01 * vinv, qn23 = q23 * vinv;
    f32x2 var01 = qn01 - me01 * me01;
    f32x2 var23 = qn23 - me23 * me23;
    const f32x2 z2 = {0.f, 0.f};
    var01 = __builtin_elementwise_max(var01, z2);
    var23 = __builtin_elementwise_max(var23, z2);
    float sd0 = sqrtf(var01.x + 1e-5f), sd1 = sqrtf(var01.y + 1e-5f);
    float sd2 = sqrtf(var23.x + 1e-5f), sd3 = sqrtf(var23.y + 1e-5f);

    u32 mep01 = pkrtz(me01.x, me01.y), mep23 = pkrtz(me23.x, me23.y);
    u32 sdp01 = pkrtz(sd0, sd1),       sdp23 = pkrtz(sd2, sd3);
    u32 mxb01 = __builtin_bit_cast(u32, mx01), mxb23 = __builtin_bit_cast(u32, mx23);
    u32 mnb01 = __builtin_bit_cast(u32, mn01), mnb23 = __builtin_bit_cast(u32, mn23);
    if (d == 0) { mxb01 = mxb23 = mnb01 = mnb23 = 0u; }

    u16* base = G + (size_t)n * D_GS;
    uint2 M; M.x = mep01; M.y = mep23;
    uint2 X; X.x = mxb01; X.y = mxb23;
    uint2 N_; N_.x = mnb01; N_.y = mnb23;
    uint2 S; S.x = sdp01; S.y = sdp23;
    *(uint2*)(base + c4)       = M;
    *(uint2*)(base + 128 + c4) = X;
    *(uint2*)(base + 256 + c4) = N_;
    *(uint2*)(base + 384 + c4) = S;
}

// h_out[n][j] = relu(bias + B*W1 + am*(S*W2) + at*(S*W3)) over logical B = [h|G]
// R4 structure (verified best: all-LDS gll16 staging, 2-barrier, 128 nodes/block,
// 2 blocks/CU; R5's counted-vmcnt BK=32 pipeline regressed -> reverted).
// ki<2 B-tiles staged from h directly; ki>=2 from the 512-col G at (k0-128).
__global__ void __launch_bounds__(256, 2) k_gemm(
        const u16* __restrict__ hin, const u16* __restrict__ G,
        const u16* __restrict__ Wt,
        const int* __restrict__ deg, const float* __restrict__ delta_p,
        const float* __restrict__ bias, u16* __restrict__ hout) {
    __shared__ _Float16 A1[128 * 64];   // 16 KB (W1)
    __shared__ _Float16 A2[128 * 64];   // 16 KB (W2)
    __shared__ _Float16 A3[128 * 64];   // 16 KB (W3)
    __shared__ _Float16 Bt[128 * 64];   // 16 KB (128-node B tile)
    const _Float16* Wf = (const _Float16*)Wt;
    const _Float16* Gf = (const _Float16*)G;
    const _Float16* Hf = (const _Float16*)hin;
    int n0 = blockIdx.x * 128;
    int t = threadIdx.x;
    int w = t >> 6, lane = t & 63;
    int srow8 = lane >> 3, sslot = lane & 7;
    int stg = (sslot ^ srow8) * 8;        // swizzled source chunk offset
    int q4 = lane >> 4, r16 = lane & 15;
    int sx0 = (q4 ^ (lane & 7)) * 8;
    int sx1 = ((q4 + 4) ^ (lane & 7)) * 8;
    int col = lane & 15;

    float delta = delta_p[0];
    float atv[8];
    _Float16 amh[8];
    #pragma unroll
    for (int nt = 0; nt < 8; nt++) {
        int node = n0 + nt * 16 + col;
        float logd = logf((float)deg[node] + 1.0f);
        amh[nt] = (_Float16)(logd / delta);
        atv[nt] = delta / fmaxf(logd, 1e-5f);
    }

    f32x4 acc[2][8], ac3[2][8];
    #pragma unroll
    for (int a = 0; a < 2; a++)
        #pragma unroll
        for (int b = 0; b < 8; b++) {
            acc[a][b] = (f32x4){0.f, 0.f, 0.f, 0.f};
            ac3[a][b] = (f32x4){0.f, 0.f, 0.f, 0.f};
        }

    for (int ki = 0; ki < 10; ki++) {
        int k0 = ki * 64;
        bool sreg = (k0 >= 128);
        __syncthreads();
        #pragma unroll
        for (int r = 0; r < 4; r++) {
            int rr = r * 4 + w;
            const _Float16* wrow = Wf + (size_t)(rr * 8 + srow8) * D_WROW;
            gll16(&A1[rr * 512], wrow + k0 + stg);
        }
        if (sreg) {
            #pragma unroll
            for (int r = 0; r < 4; r++) {
                int rr = r * 4 + w;
                const _Float16* wrow = Wf + (size_t)(rr * 8 + srow8) * D_WROW;
                gll16(&A2[rr * 512], wrow + 512 + k0 + stg);
                gll16(&A3[rr * 512], wrow + 1024 + k0 + stg);
            }
        }
        #pragma unroll
        for (int q = 0; q < 4; q++) {
            int rr = q * 4 + w;
            int row = n0 + rr * 8 + srow8;
            const _Float16* bsrc = (!sreg)
                ? Hf + (size_t)row * D_HIDC + k0 + stg
                : Gf + (size_t)row * D_GS + (k0 - 128) + stg;
            gll16(&Bt[rr * 512], bsrc);
        }
        __syncthreads();
        f16x8 a00 = *(const f16x8*)&A1[(w * 32 + r16) * 64 + sx0];
        f16x8 a01 = *(const f16x8*)&A1[(w * 32 + r16) * 64 + sx1];
        f16x8 a10 = *(const f16x8*)&A1[(w * 32 + 16 + r16) * 64 + sx0];
        f16x8 a11 = *(const f16x8*)&A1[(w * 32 + 16 + r16) * 64 + sx1];
        if (!sreg) {
            #pragma unroll
            for (int nt = 0; nt < 8; nt++) {
                f16x8 b0 = *(const f16x8*)&Bt[(nt * 16 + r16) * 64 + sx0];
                f16x8 b1 = *(const f16x8*)&Bt[(nt * 16 + r16) * 64 + sx1];
                acc[0][nt] = __builtin_amdgcn_mfma_f32_16x16x32_f16(a00, b0, acc[0][nt], 0, 0, 0);
                acc[1][nt] = __builtin_amdgcn_mfma_f32_16x16x32_f16(a10, b0, acc[1][nt], 0, 0, 0);
                acc[0][nt] = __builtin_amdgcn_mfma_f32_16x16x32_f16(a01, b1, acc[0][nt], 0, 0, 0);
                acc[1][nt] = __builtin_amdgcn_mfma_f32_16x16x32_f16(a11, b1, acc[1][nt], 0, 0, 0);
            }
        } else {
            f16x8 w2a0 = *(const f16x8*)&A2[(w * 32 + r16) * 64 + sx0];
            f16x8 w2a1 = *(const f16x8*)&A2[(w * 32 + r16) * 64 + sx1];
            f16x8 w2b0 = *(const f16x8*)&A2[(w * 32 + 16 + r16) * 64 + sx0];
            f16x8 w2b1 = *(const f16x8*)&A2[(w * 32 + 16 + r16) * 64 + sx1];
            f16x8 w3a0 = *(const f16x8*)&A3[(w * 32 + r16) * 64 + sx0];
            f16x8 w3a1 = *(const f16x8*)&A3[(w * 32 + r16) * 64 + sx1];
            f16x8 w3b0 = *(const f16x8*)&A3[(w * 32 + 16 + r16) * 64 + sx0];
            f16x8 w3b1 = *(const f16x8*)&A3[(w * 32 + 16 + r16) * 64 + sx1];
            #pragma unroll
            for (int nt = 0; nt < 8; nt++) {
                f16x8 b0 = *(const f16x8*)&Bt[(nt * 16 + r16) * 64 + sx0];
                f16x8 b1 = *(const f16x8*)&Bt[(nt * 16 + r16) * 64 + sx1];
                f16x8 bm0 = b0 * amh[nt];
                f16x8 bm1 = b1 * amh[nt];
                acc[0][nt] = __builtin_amdgcn_mfma_f32_16x16x32_f16(a00, b0, acc[0][nt], 0, 0, 0);
                acc[1][nt] = __builtin_amdgcn_mfma_f32_16x16x32_f16(a10, b0, acc[1][nt], 0, 0, 0);
                acc[0][nt] = __builtin_amdgcn_mfma_f32_16x16x32_f16(a01, b1, acc[0][nt], 0, 0, 0);
                acc[1][nt] = __builtin_amdgcn_mfma_f32_16x16x32_f16(a11, b1, acc[1][nt], 0, 0, 0);
                acc[0][nt] = __builtin_amdgcn_mfma_f32_16x16x32_f16(w2a0, bm0, acc[0][nt], 0, 0, 0);
                acc[1][nt] = __builtin_amdgcn_mfma_f32_16x16x32_f16(w2b0, bm0, acc[1][nt], 0, 0, 0);
                acc[0][nt] = __builtin_amdgcn_mfma_f32_16x16x32_f16(w2a1, bm1, acc[0][nt], 0, 0, 0);
                acc[1][nt] = __builtin_amdgcn_mfma_f32_16x16x32_f16(w2b1, bm1, acc[1][nt], 0, 0, 0);
                ac3[0][nt] = __builtin_amdgcn_mfma_f32_16x16x32_f16(w3a0, b0, ac3[0][nt], 0, 0, 0);
                ac3[1][nt] = __builtin_amdgcn_mfma_f32_16x16x32_f16(w3b0, b0, ac3[1][nt], 0, 0, 0);
                ac3[0][nt] = __builtin_amdgcn_mfma_f32_16x16x32_f16(w3a1, b1, ac3[0][nt], 0, 0, 0);
                ac3[1][nt] = __builtin_amdgcn_mfma_f32_16x16x32_f16(w3b1, b1, ac3[1][nt], 0, 0, 0);
            }
        }
    }
    // D[row=(lane>>4)*4+reg][col=lane&15]; row -> j, col -> node
    int rowq = q4 * 4;
    #pragma unroll
    for (int nt = 0; nt < 8; nt++) {
        int node = n0 + nt * 16 + col;
        float at = atv[nt];
        #pragma unroll
        for (int mt = 0; mt < 2; mt++) {
            int jb = w * 32 + mt * 16 + rowq;
            f32x4 v = acc[mt][nt], v3 = ac3[mt][nt];
            ushort4 o;
            o.x = f2h(fmaxf(v.x + at * v3.x + bias[jb], 0.0f));
            o.y = f2h(fmaxf(v.y + at * v3.y + bias[jb + 1], 0.0f));
            o.z = f2h(fmaxf(v.z + at * v3.z + bias[jb + 2], 0.0f));
            o.w = f2h(fmaxf(v.w + at * v3.w + bias[jb + 3], 0.0f));
            *(ushort4*)&hout[(size_t)node * D_HIDC + jb] = o;
        }
    }
}

// ---------------- epilogue kernels ----------------

__global__ void __launch_bounds__(256) k_pool(
        const u16* __restrict__ h, const int* __restrict__ goff,
        float* __restrict__ pooled) {
    __shared__ float sm[256];
    int g = blockIdx.x >> 2, s = blockIdx.x & 3;
    int gb = goff[g], ge = goff[g + 1];
    int len = ge - gb;
    int q = (len + 3) >> 2;
    int nb = gb + s * q;
    int ne = min(nb + q, ge);
    int t = threadIdx.x;
    int j = t & 127, half = t >> 7;
    float acc = 0.0f;
    for (int n = nb + half; n < ne; n += 2)
        acc += h2f(h[(size_t)n * D_HIDC + j]);
    sm[t] = acc; __syncthreads();
    if (t < 128) {
        float v = sm[t] + sm[t + 128];
        atomicAdd(&pooled[g * D_HIDC + j], v);
    }
}

// one block per graph; redundant mu/var recompute (pooled is tiny, L2-hot)
__global__ void __launch_bounds__(128) k_bn_fc(
        const float* __restrict__ pooled, const float* __restrict__ gamma,
        const float* __restrict__ beta, const float* __restrict__ fcW,
        const float* __restrict__ fcb, float* __restrict__ out) {
    __shared__ float bn[D_HIDC];
    int g = blockIdx.x, t = threadIdx.x;
    float s = 0.f, q = 0.f;
    for (int gg = 0; gg < N_GRAPHSC; gg++) {
        float v = pooled[gg * D_HIDC + t];
        s += v; q += v * v;
    }
    float mu = s * (1.0f / N_GRAPHSC);
    float var = q * (1.0f / N_GRAPHSC) - mu * mu;
    float inv = 1.0f / sqrtf(var + 1e-5f);
    bn[t] = (pooled[g * D_HIDC + t] - mu) * inv * gamma[t] + beta[t];
    __syncthreads();
    if (t < D_LATC) {
        float accum = fcb[t];
        for (int j = 0; j < D_HIDC; j++) accum += bn[j] * fcW[j * D_LATC + t];
        out[g * D_LATC + t] = accum;
    }
}

// ---------------- launch ----------------

extern "C" void kernel_launch(void* const* d_in, const int* in_sizes, int n_in,
                              void* d_out, int out_size, void* d_ws, size_t ws_size,
                              hipStream_t stream) {
    const float* x     = (const float*)d_in[0];
    const int*   ei    = (const int*)d_in[1];
    const int*   batch = (const int*)d_in[2];
    const float* W0 = (const float*)d_in[3];
    const float* b0 = (const float*)d_in[4];
    const float* W1 = (const float*)d_in[5];
    const float* b1 = (const float*)d_in[6];
    const float* W2 = (const float*)d_in[7];
    const float* b2 = (const float*)d_in[8];
    const float* gamma = (const float*)d_in[9];
    const float* beta  = (const float*)d_in[10];
    const float* fcW   = (const float*)d_in[11];
    const float* fcb   = (const float*)d_in[12];
    float* out = (float*)d_out;
    const int* srcv = ei;
    const int* dstv = ei + N_EDGESC;

    char* p = (char*)d_ws;
    auto alloc = [&](size_t bytes) -> char* {
        char* r = p;
        p += (bytes + 255) & ~(size_t)255;
        return r;
    };
    int*   deg_cnt = (int*)alloc((size_t)N_PAD * 4);
    int*   cursor  = (int*)alloc((size_t)N_NODESC * 4);
    float* delta_p = (float*)alloc(4);
    float* pooled  = (float*)alloc((size_t)N_GRAPHSC * D_HIDC * 4);
    char*  zero_end = p;
    int*   row_off = (int*)alloc((size_t)(N_NODESC + 1) * 4);
    int*   goff    = (int*)alloc((size_t)(N_GRAPHSC + 1) * 4);
    int*   bsum    = (int*)alloc(256 * 4);
    float* lsum    = (float*)alloc(256 * 4);
    int*   csr_src = (int*)alloc((size_t)N_EDGESC * 4);
    u16*   Wt      = (u16*)alloc((size_t)3 * D_WROW * D_HIDC * 2);   // 1.28 MB
    u16*   hA      = (u16*)alloc((size_t)N_PAD * D_HIDC * 2);        // 12.8 MB
    u16*   hB      = (u16*)alloc((size_t)N_PAD * D_HIDC * 2);        // 12.8 MB
    u16*   G       = (u16*)alloc((size_t)N_PAD * D_GS * 2);          // 51.2 MB

    int nz = (int)((zero_end - (char*)deg_cnt) / 4);
    int ZB = (nz + 255) / 256;
    int setup_grid = ZB + 12500 + 78 + 1;
    k_setup<<<setup_grid, 256, 0, stream>>>(x, W0, W1, W2, batch,
                                            hB, Wt, deg_cnt, nz, ZB, goff);
    k_count<<<(N_EDGESC + 255) / 256, 256, 0, stream>>>(dstv, deg_cnt);
    k_scan_part<<<196, 256, 0, stream>>>(deg_cnt, bsum, lsum);
    k_scan_block<<<1, 256, 0, stream>>>(bsum, lsum, delta_p);
    k_scan_final<<<196, 256, 0, stream>>>(deg_cnt, bsum, row_off);
    k_fill_csr<<<(N_EDGESC + 255) / 256, 256, 0, stream>>>(srcv, dstv, row_off, cursor, csr_src);

    const float* bs[3] = {b0, b1, b2};
    const u16* h_in[3]  = {hB, hA, hB};
    u16*       h_out[3] = {hA, hB, hA};
    size_t wsz = (size_t)D_WROW * D_HIDC;
    for (int l = 0; l < 3; l++) {
        k_aggregate<<<(N_NODESC + 7) / 8, 256, 0, stream>>>(
            h_in[l], row_off, csr_src, G);
        k_gemm<<<N_PAD / 128, 256, 0, stream>>>(
            h_in[l], G, Wt + (size_t)l * wsz, deg_cnt, delta_p, bs[l], h_out[l]);
    }
    k_pool<<<4 * N_GRAPHSC, 256, 0, stream>>>(h_out[2], goff, pooled);
    k_bn_fc<<<N_GRAPHSC, 128, 0, stream>>>(pooled, gamma, beta, fcW, fcb, out);
}